// Round 5
// baseline (364.101 us; speedup 1.0000x reference)
//
#include <hip/hip_runtime.h>

#define NN 200000
#define DD 256
#define KK 20
#define CHUNK 200            // rows per block
#define NB (NN / CHUNK)      // 1000 blocks, exact
#define RPW (CHUNK / 4)      // 50 rows per wave
#define DEPTH 8              // DMA ring slots per wave (1 KB row each)

// ---------------------------------------------------------------------------
// K1: streaming pass. Grid = NB x 256 (4 waves). Block b: rows
// [b*CHUNK,(b+1)*CHUNK); wave w handles rows 4s+w, s=0..49; 64 lanes cover
// the 256-col row as float4.
// Z path: global_load_lds DMA into a wave-PRIVATE 8-slot LDS ring, explicit
// s_waitcnt vmcnt(N) (inline asm) -- in-flight bytes live in the memory
// system, not VGPRs (R2-R4 register pipelines all spilled: R4 WRITE_SIZE
// 89MB). 12 waves/CU x 7 KB outstanding = 84 KB/CU >> ~25 KB latency-BW
// product. vmcnt retires in issue order, so vmcnt(7) with 8 outstanding
// guarantees the oldest slot has landed. No barrier in the loop.
// P path: 16 KB slice staged to LDS once, broadcast ds_read per row.
// amdgpu_waves_per_eu(3,3) pins the allocator at 3 waves/EU (~170-reg
// budget for ~110 demand) so it cannot spill chasing occupancy (R4 failure).
// ---------------------------------------------------------------------------

typedef __attribute__((address_space(3))) unsigned int lds_uint;
typedef const __attribute__((address_space(1))) unsigned int glb_uint;
#define DMA(gp, lp) \
  __builtin_amdgcn_global_load_lds((glb_uint*)(gp), (lds_uint*)(lp), 16, 0, 0)
#define WAITVM(N) asm volatile("s_waitcnt vmcnt(" #N ")" ::: "memory")

#define SCOMP(i, zv)                                                        \
  {                                                                         \
    const float4* pr_ = (const float4*)(pl + (((i) * 4 + w) * KK));         \
    float4 p0_ = pr_[0], p1_ = pr_[1], p2_ = pr_[2], p3_ = pr_[3],          \
           p4_ = pr_[4];                                                    \
    float zz_[4] = {zv.x, zv.y, zv.z, zv.w};                                \
    float pv_[KK] = {p0_.x, p0_.y, p0_.z, p0_.w, p1_.x, p1_.y, p1_.z,       \
                     p1_.w, p2_.x, p2_.y, p2_.z, p2_.w, p3_.x, p3_.y,       \
                     p3_.z, p3_.w, p4_.x, p4_.y, p4_.z, p4_.w};             \
    t1 += zz_[0] * zz_[0] + zz_[1] * zz_[1];                                \
    t1 += zz_[2] * zz_[2] + zz_[3] * zz_[3];                                \
    _Pragma("unroll") for (int k_ = 0; k_ < KK; ++k_) {                     \
      _Pragma("unroll") for (int c_ = 0; c_ < 4; ++c_)                      \
          acc[k_][c_] += zz_[c_] * pv_[k_];                                 \
    }                                                                       \
  }

// Tail iteration S with exactly (N+1) DMAs outstanding before the wait.
#define TAIL(S, N)                                                          \
  {                                                                         \
    WAITVM(N);                                                              \
    float4 z = ((const float4*)(myring + ((S) & (DEPTH - 1)) * DD))[lane];  \
    SCOMP(S, z);                                                            \
  }

__global__ __launch_bounds__(256)
__attribute__((amdgpu_waves_per_eu(3, 3))) void egac_main(
    const float* __restrict__ Z, const float* __restrict__ P,
    float* __restrict__ ztp_part, float* __restrict__ t1_part) {
  __shared__ float ring[4 * DEPTH * DD];  // 32 KB: 4 waves x 8 x 1KB rows
  __shared__ float pl[CHUNK * KK];        // 16 KB P slice
  __shared__ float wsum[4];

  const int t = threadIdx.x;
  const int lane = t & 63;
  const int w = t >> 6;  // wave id (wave-uniform)
  const int b = blockIdx.x;
  const int base = b * CHUNK;

  // ---- stage P slice into LDS (coalesced float4) ----
  {
    const float4* Ps = (const float4*)(P + (size_t)base * KK);
    float4* pd = (float4*)pl;
    for (int i = t; i < CHUNK * KK / 4; i += 256) pd[i] = Ps[i];
  }
  __syncthreads();  // drains vmcnt: ring accounting starts at 0 outstanding

  float acc[KK][4];
#pragma unroll
  for (int k = 0; k < KK; ++k)
#pragma unroll
    for (int c = 0; c < 4; ++c) acc[k][c] = 0.f;
  float t1 = 0.f;

  const float* Zblk = Z + (size_t)base * DD;
  float* myring = ring + w * (DEPTH * DD);

  // ---- prologue: fill the ring (8 row-DMAs in flight) ----
#pragma unroll
  for (int q = 0; q < DEPTH; ++q)
    DMA(Zblk + (4 * q + w) * DD + lane * 4, myring + q * DD);

  // ---- main loop: s = 0..41, always 8 outstanding ----
  for (int s = 0; s < RPW - DEPTH; ++s) {
    WAITVM(7);  // oldest (slot s&7) has landed
    float4 z = ((const float4*)(myring + (s & (DEPTH - 1)) * DD))[lane];
    asm volatile("" ::: "memory");  // ds_read issued before slot reuse below
    DMA(Zblk + (4 * (s + DEPTH) + w) * DD + lane * 4,
        myring + (s & (DEPTH - 1)) * DD);
    SCOMP(s, z);
  }
  // ---- tail: s = 42..49, outstanding drains 8 -> 1 ----
  TAIL(42, 7); TAIL(43, 6); TAIL(44, 5); TAIL(45, 4);
  TAIL(46, 3); TAIL(47, 2); TAIL(48, 1); TAIL(49, 0);

  // ---- intra-block reduction over the 4 waves (ring LDS reused) ----
  __syncthreads();
  float(*red)[DD] = (float(*)[DD])ring;  // 20 KB <= 32 KB ring
  for (int ph = 0; ph < 4; ++ph) {
    if (w == ph) {
      if (ph == 0) {
#pragma unroll
        for (int k = 0; k < KK; ++k)
          ((float4*)&red[k][0])[lane] =
              make_float4(acc[k][0], acc[k][1], acc[k][2], acc[k][3]);
      } else {
#pragma unroll
        for (int k = 0; k < KK; ++k) {
          float4 r = ((float4*)&red[k][0])[lane];
          r.x += acc[k][0];
          r.y += acc[k][1];
          r.z += acc[k][2];
          r.w += acc[k][3];
          ((float4*)&red[k][0])[lane] = r;
        }
      }
    }
    __syncthreads();
  }

  // term1: per-wave shuffle reduce, 4 wave leaders -> LDS
#pragma unroll
  for (int off = 32; off > 0; off >>= 1) t1 += __shfl_xor(t1, off, 64);
  if (lane == 0) wsum[w] = t1;
  __syncthreads();

  // coalesced float4 write-out of the 5120-float block partial
  float4* dst = (float4*)(ztp_part + (size_t)b * (KK * DD));
  const float4* src = (const float4*)&red[0][0];
#pragma unroll
  for (int i = 0; i < (KK * DD) / (4 * 256); ++i)
    dst[i * 256 + t] = src[i * 256 + t];
  if (t == 0) t1_part[b] = wsum[0] + wsum[1] + wsum[2] + wsum[3];
}

// ---------------------------------------------------------------------------
// K2: cross-block reduction + final scalar. Grid = 160 x 512. Block handles
// 32 ztp entries; thread (psub=t>>5, el=t&31) sums partials p = psub,
// psub+16, ...; LDS tree over 16 psubs; square-sum -> one atomicAdd/block.
// Block 0 folds in term1. d_out zeroed via hipMemsetAsync first.
// ---------------------------------------------------------------------------
__global__ __launch_bounds__(512) void egac_reduce(
    const float* __restrict__ ztp_part, const float* __restrict__ t1_part,
    float* __restrict__ out, int nb) {
  __shared__ float red[16][32];
  const int t = threadIdx.x;
  const int el = t & 31;
  const int ps = t >> 5;
  const int e = blockIdx.x * 32 + el;

  float s = 0.f;
  for (int p = ps; p < nb; p += 16) s += ztp_part[(size_t)p * (KK * DD) + e];
  red[ps][el] = s;
  __syncthreads();
  for (int sh = 8; sh >= 1; sh >>= 1) {
    if (ps < sh) red[ps][el] += red[ps + sh][el];
    __syncthreads();
  }
  if (t == 0) {
    float ssq = 0.f;
#pragma unroll
    for (int i = 0; i < 32; ++i) {
      float v = red[0][i];
      ssq += v * v;
    }
    atomicAdd(out, -ssq);  // term2 enters negatively
  }

  if (blockIdx.x == 0) {
    float v = 0.f;
    for (int i = t; i < nb; i += 512) v += t1_part[i];
#pragma unroll
    for (int off = 32; off > 0; off >>= 1) v += __shfl_xor(v, off, 64);
    __shared__ float w2[8];
    if ((t & 63) == 0) w2[t >> 6] = v;
    __syncthreads();
    if (t == 0) {
      float tt = 0.f;
#pragma unroll
      for (int i = 0; i < 8; ++i) tt += w2[i];
      atomicAdd(out, tt);  // + term1
    }
  }
}

extern "C" void kernel_launch(void* const* d_in, const int* in_sizes, int n_in,
                              void* d_out, int out_size, void* d_ws,
                              size_t ws_size, hipStream_t stream) {
  const float* Z = (const float*)d_in[0];
  const float* P = (const float*)d_in[1];
  float* out = (float*)d_out;

  float* ztp_part = (float*)d_ws;
  float* t1_part = (float*)d_ws + (size_t)NB * KK * DD;

  hipMemsetAsync(d_out, 0, sizeof(float), stream);
  egac_main<<<NB, 256, 0, stream>>>(Z, P, ztp_part, t1_part);
  egac_reduce<<<160, 512, 0, stream>>>(ztp_part, t1_part, out, NB);
}

// Round 6
// 325.427 us; speedup vs baseline: 1.1188x; 1.1188x over previous
//
#include <hip/hip_runtime.h>

#define NN 200000
#define DD 256
#define KK 20
#define CHUNK 200             // rows per block
#define NB (NN / CHUNK)       // 1000 blocks, exact
#define TROWS 20              // rows per stage (20 KB)
#define NSTG (CHUNK / TROWS)  // 10 stages, no tail

// ---------------------------------------------------------------------------
// K1: streaming pass, one COLUMN per thread. Grid = NB x 256 (4 waves).
// Thread t owns column t for all of its block's rows: acc[KK]=20 VGPRs,
// z = 1 ds_read_b32/row, P[row][0..19] is block-uniform -> SGPRs via
// readfirstlane (v_fmac with SGPR operand). Total ~40 VGPR demand: the
// R2-R5 killer (allocator pinning 84 arch-VGPRs -> scratch spill, R5
// WRITE_SIZE=125MB) cannot recur -- there is nothing left to spill.
// Z path: m97-style global_load_lds double buffer (2 x TROWS x 1KB =
// 40960 B exactly -> 4 blocks/CU, 16 waves/CU, 80 KB/CU DMA in flight).
// Wave w DMAs rows 5w..5w+4 of each stage; __syncthreads per stage is the
// only drain (m97 plateau tax ~20%, acceptable).
// No cross-wave reduction: columns are thread-partitioned; acc goes
// straight to ztp_part (20 coalesced dword stores).
// ---------------------------------------------------------------------------

typedef __attribute__((address_space(3))) unsigned int lds_uint;
typedef const __attribute__((address_space(1))) unsigned int glb_uint;
#define DMA(gp, lp) \
  __builtin_amdgcn_global_load_lds((glb_uint*)(gp), (lds_uint*)(lp), 16, 0, 0)

__global__ __launch_bounds__(256) void egac_main(
    const float* __restrict__ Z, const float* __restrict__ P,
    float* __restrict__ ztp_part, float* __restrict__ t1_part) {
  __shared__ float ring[2][TROWS * DD];  // 40960 B total -> 4 blocks/CU

  const int t = threadIdx.x;
  const int lane = t & 63;
  const int w = t >> 6;  // wave id (wave-uniform)
  const int b = blockIdx.x;
  const int base = b * CHUNK;

  const float* Zblk = Z + (size_t)base * DD;

  float acc[KK];
#pragma unroll
  for (int k = 0; k < KK; ++k) acc[k] = 0.f;
  float t1 = 0.f;

  // ---- prologue: DMA stage 0 (wave w loads rows 5w..5w+4, 1 KB each) ----
#pragma unroll
  for (int q = 0; q < TROWS / 4; ++q) {
    const int rl = 5 * w + q;
    DMA(Zblk + rl * DD + lane * 4, &ring[0][rl * DD]);
  }
  __syncthreads();  // drains prologue DMAs

  for (int s = 0; s < NSTG; ++s) {
    const int cur = s & 1;
    if (s + 1 < NSTG) {
#pragma unroll
      for (int q = 0; q < TROWS / 4; ++q) {
        const int rl = 5 * w + q;
        DMA(Zblk + ((s + 1) * TROWS + rl) * DD + lane * 4,
            &ring[cur ^ 1][rl * DD]);
      }
    }
    const float* zbuf = &ring[cur][0];
#pragma unroll
    for (int i = 0; i < TROWS; ++i) {
      float z = zbuf[i * DD + t];  // ds_read_b32, lanes consecutive
      // block-uniform row -> force scalar (s_load) path for P
      const int ro = __builtin_amdgcn_readfirstlane((base + s * TROWS + i) * KK);
      const float* pr = P + ro;
      t1 += z * z;
#pragma unroll
      for (int k = 0; k < KK; ++k) acc[k] += z * pr[k];  // v_fmac v,s,v
    }
    __syncthreads();  // stage flip: drains next-stage DMAs + ds_reads
  }

  // ---- write the block partial: thread t owns column t ----
#pragma unroll
  for (int k = 0; k < KK; ++k)
    ztp_part[(size_t)b * (KK * DD) + k * DD + t] = acc[k];

  // term1: per-wave shuffle reduce; wsum reuses dead ring LDS
#pragma unroll
  for (int off = 32; off > 0; off >>= 1) t1 += __shfl_xor(t1, off, 64);
  float* wsum = &ring[0][0];  // ring dead after last barrier
  if (lane == 0) wsum[w] = t1;
  __syncthreads();
  if (t == 0) t1_part[b] = wsum[0] + wsum[1] + wsum[2] + wsum[3];
}

// ---------------------------------------------------------------------------
// K2: cross-block reduction + final scalar. Grid = 160 x 512. Block handles
// 32 ztp entries; thread (psub=t>>5, el=t&31) sums partials p = psub,
// psub+16, ...; LDS tree over 16 psubs; square-sum -> one atomicAdd/block.
// Block 0 folds in term1. d_out zeroed via hipMemsetAsync first.
// ---------------------------------------------------------------------------
__global__ __launch_bounds__(512) void egac_reduce(
    const float* __restrict__ ztp_part, const float* __restrict__ t1_part,
    float* __restrict__ out, int nb) {
  __shared__ float red[16][32];
  const int t = threadIdx.x;
  const int el = t & 31;
  const int ps = t >> 5;
  const int e = blockIdx.x * 32 + el;

  float s = 0.f;
  for (int p = ps; p < nb; p += 16) s += ztp_part[(size_t)p * (KK * DD) + e];
  red[ps][el] = s;
  __syncthreads();
  for (int sh = 8; sh >= 1; sh >>= 1) {
    if (ps < sh) red[ps][el] += red[ps + sh][el];
    __syncthreads();
  }
  if (t == 0) {
    float ssq = 0.f;
#pragma unroll
    for (int i = 0; i < 32; ++i) {
      float v = red[0][i];
      ssq += v * v;
    }
    atomicAdd(out, -ssq);  // term2 enters negatively
  }

  if (blockIdx.x == 0) {
    float v = 0.f;
    for (int i = t; i < nb; i += 512) v += t1_part[i];
#pragma unroll
    for (int off = 32; off > 0; off >>= 1) v += __shfl_xor(v, off, 64);
    __shared__ float w2[8];
    if ((t & 63) == 0) w2[t >> 6] = v;
    __syncthreads();
    if (t == 0) {
      float tt = 0.f;
#pragma unroll
      for (int i = 0; i < 8; ++i) tt += w2[i];
      atomicAdd(out, tt);  // + term1
    }
  }
}

extern "C" void kernel_launch(void* const* d_in, const int* in_sizes, int n_in,
                              void* d_out, int out_size, void* d_ws,
                              size_t ws_size, hipStream_t stream) {
  const float* Z = (const float*)d_in[0];
  const float* P = (const float*)d_in[1];
  float* out = (float*)d_out;

  float* ztp_part = (float*)d_ws;
  float* t1_part = (float*)d_ws + (size_t)NB * KK * DD;

  hipMemsetAsync(d_out, 0, sizeof(float), stream);
  egac_main<<<NB, 256, 0, stream>>>(Z, P, ztp_part, t1_part);
  egac_reduce<<<160, 512, 0, stream>>>(ztp_part, t1_part, out, NB);
}